// Round 16
// baseline (149.100 us; speedup 1.0000x reference)
//
#include <hip/hip_runtime.h>
#include <math.h>

#define Bn 2
#define CIc 256
#define COc 256
#define Hh 128
#define Ww 128
#define HW (Hh*Ww)

typedef unsigned short u16;
typedef unsigned int u32;
typedef __bf16 bf16x8 __attribute__((ext_vector_type(8)));
typedef float  f32x4  __attribute__((ext_vector_type(4)));
typedef float  f32x2  __attribute__((ext_vector_type(2)));
typedef u32    u32x4v __attribute__((ext_vector_type(4)));

// ws layout (float offsets)
#define WOFP_OFF  0          // 9*8*32*4*8 u16  = 36864 f
#define WPACK_OFF 36864      // 9*8*256*4*8 u16 = 294912 f
#define SCALE_OFF 331776
#define SHIFT_OFF 332032
#define XT_OFF    332288     // u16 xt[B][HW][256]
// xt pixel-row: 32 units of 16B; unit u holds ci chunk (u&3)*64 + (u>>2)*8 .. +8
// A-packs use the same map (unit s*4+kb <-> ci = kb*64 + s*8 + j) so the permutation cancels.

__device__ __forceinline__ u16 f2bf(float f) {
    u32 u = __builtin_bit_cast(u32, f);
    return (u16)((u + 0x7FFFu + ((u >> 16) & 1u)) >> 16);
}
__device__ __forceinline__ u32 pkbf(float lo, float hi) {
    __bf16 a = (__bf16)lo, b = (__bf16)hi;            // fuses to v_cvt_pk_bf16_f32
    return (u32)__builtin_bit_cast(u16, a) | ((u32)__builtin_bit_cast(u16, b) << 16);
}
__device__ __forceinline__ f32x2 unpk(u32 u) {
    f32x2 r;
    r.x = __builtin_bit_cast(float, u << 16);
    r.y = __builtin_bit_cast(float, u & 0xFFFF0000u);
    return r;
}

__global__ void prep_kernel(const float* __restrict__ w_off,
                            const float* __restrict__ w_dcn,
                            const float* __restrict__ b_dcn,
                            const float* __restrict__ gamma,
                            const float* __restrict__ beta,
                            const float* __restrict__ rmean,
                            const float* __restrict__ rvar,
                            float* __restrict__ ws) {
    int tid = blockIdx.x*blockDim.x + threadIdx.x;
    int nth = gridDim.x*blockDim.x;
    u16* wofp = (u16*)(ws + WOFP_OFF);
    u16* wpk  = (u16*)(ws + WPACK_OFF);
    for (int idx = tid; idx < 9*8*32*4*8; idx += nth) {
        int j = idx & 7, kb = (idx>>3)&3, co = (idx>>5)&31, s = (idx>>10)&7, k = idx>>13;
        int ci = kb*64 + s*8 + j;
        float v = (co < 27) ? w_off[(co*CIc + ci)*9 + k] : 0.f;
        wofp[idx] = f2bf(v);
    }
    for (int idx = tid; idx < 9*8*256*4*8; idx += nth) {
        int j = idx & 7, kb = (idx>>3)&3, co = (idx>>5)&255, s = (idx>>13)&7, k = idx>>16;
        int ci = kb*64 + s*8 + j;
        wpk[idx] = f2bf(w_dcn[(co*CIc + ci)*9 + k]);
    }
    if (tid < COc) {
        float inv = gamma[tid] * rsqrtf(rvar[tid] + 1e-5f);
        ws[SCALE_OFF+tid] = inv;
        ws[SHIFT_OFF+tid] = beta[tid] - rmean[tid]*inv + b_dcn[tid]*inv;
    }
}

// NCHW fp32 -> permuted NHWC bf16. Block: 32px x 256ci.
__global__ __launch_bounds__(256) void transpose_kernel(const float* __restrict__ x,
                                                        float* __restrict__ ws) {
    __shared__ float tile[256][33];
    int bid = blockIdx.x;                 // Bn*512 = 1024
    int b   = bid >> 9;
    int pxt = bid & 511;                  // 32-pixel group
    const float* xb = x + (size_t)b*CIc*HW + pxt*32;
    int px = threadIdx.x & 31, cg = threadIdx.x >> 5;      // cg in [0,8)
    #pragma unroll 8
    for (int it = 0; it < 32; it++) {
        int ci = it*8 + cg;
        tile[ci][px] = xb[(size_t)ci*HW + px];
    }
    __syncthreads();
    int px2 = threadIdx.x >> 3, oct = threadIdx.x & 7;     // px2 in [0,32)
    u16* xto = (u16*)(ws + XT_OFF) + (((size_t)b*HW + pxt*32 + px2) << 8);
    #pragma unroll
    for (int uu = 0; uu < 4; uu++) {
        int u = uu*8 + oct;
        int cib = (u & 3)*64 + (u >> 2)*8;
        u32x4v v;
        #pragma unroll
        for (int t = 0; t < 4; t++)
            v[t] = pkbf(tile[cib + 2*t][px2], tile[cib + 2*t + 1][px2]);
        *(u32x4v*)(xto + u*8) = v;
    }
}

// corner weights + corner row pointers (incl. sub8 16B slot) for pixel p, tap k
__device__ __forceinline__ void calc_corners(const float* spy, const float* spxs, const float* smk,
        int k, int p_s, int sub8, const u16* xt,
        float& w00, float& w01, float& w10, float& w11,
        const u16*& x00, const u16*& x01, const u16*& x10, const u16*& x11) {
    float pyv = spy[k*32 + p_s], pxv = spxs[k*32 + p_s], mv = smk[k*32 + p_s];
    float y0f = floorf(pyv), x0f = floorf(pxv);
    float ly = pyv - y0f, lx = pxv - x0f;
    int y0 = (int)y0f, x0i = (int)x0f;
    int y1 = y0 + 1, x1i = x0i + 1;
    float wy0 = ((unsigned)y0  < Hh) ? (1.f-ly) : 0.f;
    float wy1 = ((unsigned)y1  < Hh) ? ly       : 0.f;
    float wx0 = ((unsigned)x0i < Ww) ? (1.f-lx) : 0.f;
    float wx1 = ((unsigned)x1i < Ww) ? lx       : 0.f;
    w00 = wy0*wx0*mv; w01 = wy0*wx1*mv; w10 = wy1*wx0*mv; w11 = wy1*wx1*mv;
    int cy0 = min(max(y0,0),Hh-1), cy1 = min(max(y1,0),Hh-1);
    int cx0 = min(max(x0i,0),Ww-1), cx1 = min(max(x1i,0),Ww-1);
    x00 = xt + ((((cy0<<7)+cx0)<<8) + sub8*8);
    x01 = xt + ((((cy0<<7)+cx1)<<8) + sub8*8);
    x10 = xt + ((((cy1<<7)+cx0)<<8) + sub8*8);
    x11 = xt + ((((cy1<<7)+cx1)<<8) + sub8*8);
}

// gather one 16B slot of 128B-group u (0..3) from 4 corners (group step = 64 u16)
#define LOAD1(gg, u) { \
    gg[0] = *(const u32x4v*)(x00 + ((u) << 6)); \
    gg[1] = *(const u32x4v*)(x01 + ((u) << 6)); \
    gg[2] = *(const u32x4v*)(x10 + ((u) << 6)); \
    gg[3] = *(const u32x4v*)(x11 + ((u) << 6)); }

// interp + ds_write_b128 of group u's slot sub8
#define CONS1(gg, u, dst) { \
    u32x4v vv; \
    _Pragma("unroll") for (int w2 = 0; w2 < 4; w2++) { \
        f32x2 r = unpk(gg[0][w2])*w00 + unpk(gg[1][w2])*w01 \
                + unpk(gg[2][w2])*w10 + unpk(gg[3][w2])*w11; \
        vv[w2] = pkbf(r.x, r.y); \
    } \
    *(u32x4v*)((dst) + wrbase0 + ((u32)(((u) << 7) | (sub8 << 4)) ^ wswz)) = vv; }

// one MFMA s-step: 2 B-reads (32px) + 8 MFMA on apre[s&1]
#define GEMMSTEP(s) { \
    u32 inn = ((u32)((s)*64 + kb*16)) ^ rswz; \
    _Pragma("unroll") for (int bq = 0; bq < 2; bq++) { \
        bf16x8 bb = *(const bf16x8*)(base_r + (pxl + bq*16)*512 + inn); \
        _Pragma("unroll") for (int mi = 0; mi < 4; mi++) \
            acc[mi][bq] = __builtin_amdgcn_mfma_f32_16x16x32_bf16(apre[(s)&1][mi], bb, acc[mi][bq], 0,0,0); \
    } }

#define APREF(ptr) { \
    _Pragma("unroll") for (int mi = 0; mi < 4; mi++) \
        apre[s&1][mi] = *(const bf16x8*)((ptr) + mi*512); }

// Fused: 32px tile, 1024 blocks (4 blocks/CU), 256 threads / 4 waves,
// wave = 64co x 32px (acc 32). R14 schedule kept: dbuf, 1 barrier/k,
// [fence][MFMA][A-prefetch depth2][gather slots]. LDS 35.5KB.
__global__ __launch_bounds__(256, 3) void fused_kernel(const float* __restrict__ b_off,
                                                       const float* __restrict__ ws,
                                                       float* __restrict__ out) {
    __shared__ __align__(16) char smem[32768 + 3*288*4];
    float* fin  = (float*)smem;               // [32][32] f32, phase A only (aliases buf0)
    float* spy  = (float*)(smem + 32768);
    float* spxs = spy + 288;
    float* smk  = spxs + 288;

    int tid = threadIdx.x;
    int bid = blockIdx.x;
    int tile = (bid & 7)*128 + (bid >> 3);    // XCD-chunked swizzle, 1024 blocks
    int b = tile >> 9;
    int pixbase = (tile & 511) * 32;
    int h  = pixbase >> 7;
    int w0 = pixbase & 127;                   // 0,32,64,96

    const u16* wofp = (const u16*)(ws + WOFP_OFF);
    const u16* wpk  = (const u16*)(ws + WPACK_OFF);
    const u16* xt   = (const u16*)(ws + XT_OFF) + (size_t)b*HW*256;

    int l  = tid & 63;
    int wv = tid >> 6;                        // 0..3
    int kb = l >> 4;
    int pxl = l & 15;
    int aoff = pxl*32 + kb*8;

    // ---------------- phase A: offset conv (waves 0,1: 16px each, 32co) ----------------
    if (wv < 2) {
        int pxa = wv*16 + pxl;
        f32x4 oa0 = {0.f,0.f,0.f,0.f}, oa1 = {0.f,0.f,0.f,0.f};
        #pragma unroll
        for (int k = 0; k < 9; k++) {
            int ky = k/3, kx = k - 3*ky;
            int y  = h + ky - 1;
            int xw = w0 + pxa + kx - 1;
            bool ok = ((unsigned)y < Hh) && ((unsigned)xw < Ww);
            const u16* brow = xt + (((y << 7) + xw) << 8);
            const u16* wk = wofp + k*8192;
            #pragma unroll
            for (int s = 0; s < 8; s++) {
                bf16x8 bf = {};
                if (ok) bf = *(const bf16x8*)(brow + s*32 + kb*8);
                bf16x8 a0 = *(const bf16x8*)(wk + s*1024 + aoff);
                bf16x8 a1 = *(const bf16x8*)(wk + s*1024 + 512 + aoff);
                oa0 = __builtin_amdgcn_mfma_f32_16x16x32_bf16(a0, bf, oa0, 0,0,0);
                oa1 = __builtin_amdgcn_mfma_f32_16x16x32_bf16(a1, bf, oa1, 0,0,0);
            }
        }
        #pragma unroll
        for (int r = 0; r < 4; r++) {
            fin[(kb*4 + r)*32 + pxa]      = oa0[r];
            fin[(16 + kb*4 + r)*32 + pxa] = oa1[r];
        }
    }
    __syncthreads();
    // FIX vs R15: grid-stride so ALL 288 entries (incl. tap k=8) are written.
    for (int idx = tid; idx < 288; idx += 256) {
        int k = idx >> 5, p = idx & 31;
        float dy = fin[(2*k)*32 + p]   + b_off[2*k];
        float dx = fin[(2*k+1)*32 + p] + b_off[2*k+1];
        float mv = fin[(18+k)*32 + p]  + b_off[18+k];
        spy[idx]  = (float)(h - 1 + k/3) + dy;
        spxs[idx] = (float)(w0 + p - 1 + k%3) + dx;
        smk[idx]  = 1.f/(1.f + __expf(-mv));
    }
    __syncthreads();

    // ---------------- phase B ----------------
    int p_s = tid >> 3;                       // staging pixel 0..31
    int sub8 = tid & 7;                       // 16B slot within each 128B group
    u32 wrbase0 = (u32)p_s*512;
    u32 wswz = (u32)(p_s & 7) << 4;
    u32 rswz = (u32)(pxl & 7) << 4;

    f32x4 acc[4][2];
    #pragma unroll
    for (int mi = 0; mi < 4; mi++) {
        acc[mi][0] = (f32x4){0.f,0.f,0.f,0.f};
        acc[mi][1] = (f32x4){0.f,0.f,0.f,0.f};
    }

    bf16x8 apre[2][4];
    u32x4v g0[4], g1[4];

    // --- prologue: stage k=0 into buf0, preload A(0,s=0),A(0,s=1) ---
    {
        float w00,w01,w10,w11; const u16 *x00,*x01,*x10,*x11;
        calc_corners(spy, spxs, smk, 0, p_s, sub8, xt, w00,w01,w10,w11, x00,x01,x10,x11);
        LOAD1(g0, 0); LOAD1(g1, 1);
        CONS1(g0, 0, smem); LOAD1(g0, 2);
        CONS1(g1, 1, smem); LOAD1(g1, 3);
        CONS1(g0, 2, smem);
        CONS1(g1, 3, smem);
    }
    {
        const u16* ap0 = wpk + wv*2048 + aoff;
        #pragma unroll
        for (int mi = 0; mi < 4; mi++) {
            apre[0][mi] = *(const bf16x8*)(ap0 + mi*512);
            apre[1][mi] = *(const bf16x8*)(ap0 + 8192 + mi*512);
        }
    }
    __syncthreads();

    // main loop k = 0..7 (stage k+1), k=8 peeled below
    for (int k = 0; k < 8; k++) {
        const char* base_r = smem + ((k & 1) << 14);
        char* base_w = smem + (((k + 1) & 1) << 14);
        const u16* wkb   = wpk + k*65536 + wv*2048 + aoff;
        const u16* wkb_n = wkb + 65536;

        float w00,w01,w10,w11; const u16 *x00,*x01,*x10,*x11;
        calc_corners(spy, spxs, smk, k+1, p_s, sub8, xt, w00,w01,w10,w11, x00,x01,x10,x11);

        #pragma unroll
        for (int s = 0; s < 8; s++) {
            __builtin_amdgcn_sched_barrier(0);
            __builtin_amdgcn_s_setprio(1);
            GEMMSTEP(s);
            __builtin_amdgcn_s_setprio(0);
            // A(step+2), post-MFMA — AHEAD of gathers in the vmcnt FIFO
            { const u16* ap = (s < 6) ? (wkb + (s+2)*8192) : (wkb_n + (s-6)*8192); APREF(ap); }
            // gather slots for k+1 (4 units, 2 live, distances >=3)
            if (s == 0) { LOAD1(g0, 0); }
            if (s == 1) { LOAD1(g1, 1); }
            if (s == 4) { CONS1(g0, 0, base_w); LOAD1(g0, 2); }
            if (s == 5) { CONS1(g1, 1, base_w); LOAD1(g1, 3); }
            if (s == 7) { CONS1(g0, 2, base_w); }
        }
        CONS1(g1, 3, base_w);
        __syncthreads();
    }
    // k = 8 peeled: pure GEMM on buf0
    {
        const char* base_r = smem;
        const u16* wkb = wpk + 8*65536 + wv*2048 + aoff;
        #pragma unroll
        for (int s = 0; s < 8; s++) {
            __builtin_amdgcn_sched_barrier(0);
            __builtin_amdgcn_s_setprio(1);
            GEMMSTEP(s);
            __builtin_amdgcn_s_setprio(0);
            if (s < 6) { const u16* ap = wkb + (s+2)*8192; APREF(ap); }
        }
    }

    // epilogue: BN + ReLU. D layout: col(px)=pxl, row(co)=kb*4+r
    int rbase = kb*4;
    #pragma unroll
    for (int mi = 0; mi < 4; mi++) {
        #pragma unroll
        for (int r = 0; r < 4; r++) {
            int co = wv*64 + mi*16 + rbase + r;
            float sc = ws[SCALE_OFF+co], sh = ws[SHIFT_OFF+co];
            float* op = out + ((size_t)(b*COc + co))*HW + pixbase + pxl;
            op[0]  = fmaxf(acc[mi][0][r]*sc + sh, 0.f);
            op[16] = fmaxf(acc[mi][1][r]*sc + sh, 0.f);
        }
    }
}

extern "C" void kernel_launch(void* const* d_in, const int* in_sizes, int n_in,
                              void* d_out, int out_size, void* d_ws, size_t ws_size,
                              hipStream_t stream) {
    const float* x     = (const float*)d_in[0];
    const float* w_off = (const float*)d_in[1];
    const float* b_off = (const float*)d_in[2];
    const float* w_dcn = (const float*)d_in[3];
    const float* b_dcn = (const float*)d_in[4];
    const float* gamma = (const float*)d_in[5];
    const float* beta  = (const float*)d_in[6];
    const float* rmean = (const float*)d_in[7];
    const float* rvar  = (const float*)d_in[8];
    float* out = (float*)d_out;
    float* ws  = (float*)d_ws;

    prep_kernel<<<512, 256, 0, stream>>>(w_off, w_dcn, b_dcn, gamma, beta, rmean, rvar, ws);
    transpose_kernel<<<1024, 256, 0, stream>>>(x, ws);
    fused_kernel<<<1024, 256, 0, stream>>>(b_off, ws, out);
}

// Round 18
// 110.514 us; speedup vs baseline: 1.3492x; 1.3492x over previous
//
#include <hip/hip_runtime.h>
#include <math.h>

#define Bn 2
#define CIc 256
#define COc 256
#define Hh 128
#define Ww 128
#define HW (Hh*Ww)

typedef unsigned short u16;
typedef unsigned int u32;
typedef __bf16 bf16x8 __attribute__((ext_vector_type(8)));
typedef float  f32x4  __attribute__((ext_vector_type(4)));
typedef float  f32x2  __attribute__((ext_vector_type(2)));
typedef u32    u32x4v __attribute__((ext_vector_type(4)));

// ws layout (float offsets)
#define WOFP_OFF  0          // 9*8*32*4*8 u16  = 36864 f
#define WPACK_OFF 36864      // 9*8*256*4*8 u16 = 294912 f
#define SCALE_OFF 331776
#define SHIFT_OFF 332032
#define XT_OFF    332288     // u16 xt[B][HW][256]
// xt pixel-row: 32 units of 16B; unit u holds ci chunk (u&3)*64 + (u>>2)*8 .. +8
// A-packs use the same map (unit s*4+kb <-> ci = kb*64 + s*8 + j) so the permutation cancels.

__device__ __forceinline__ u16 f2bf(float f) {
    u32 u = __builtin_bit_cast(u32, f);
    return (u16)((u + 0x7FFFu + ((u >> 16) & 1u)) >> 16);
}
__device__ __forceinline__ u32 pkbf(float lo, float hi) {
    __bf16 a = (__bf16)lo, b = (__bf16)hi;            // fuses to v_cvt_pk_bf16_f32
    return (u32)__builtin_bit_cast(u16, a) | ((u32)__builtin_bit_cast(u16, b) << 16);
}
__device__ __forceinline__ f32x2 unpk(u32 u) {
    f32x2 r;
    r.x = __builtin_bit_cast(float, u << 16);
    r.y = __builtin_bit_cast(float, u & 0xFFFF0000u);
    return r;
}

__global__ void prep_kernel(const float* __restrict__ w_off,
                            const float* __restrict__ w_dcn,
                            const float* __restrict__ b_dcn,
                            const float* __restrict__ gamma,
                            const float* __restrict__ beta,
                            const float* __restrict__ rmean,
                            const float* __restrict__ rvar,
                            float* __restrict__ ws) {
    int tid = blockIdx.x*blockDim.x + threadIdx.x;
    int nth = gridDim.x*blockDim.x;
    u16* wofp = (u16*)(ws + WOFP_OFF);
    u16* wpk  = (u16*)(ws + WPACK_OFF);
    for (int idx = tid; idx < 9*8*32*4*8; idx += nth) {
        int j = idx & 7, kb = (idx>>3)&3, co = (idx>>5)&31, s = (idx>>10)&7, k = idx>>13;
        int ci = kb*64 + s*8 + j;
        float v = (co < 27) ? w_off[(co*CIc + ci)*9 + k] : 0.f;
        wofp[idx] = f2bf(v);
    }
    for (int idx = tid; idx < 9*8*256*4*8; idx += nth) {
        int j = idx & 7, kb = (idx>>3)&3, co = (idx>>5)&255, s = (idx>>13)&7, k = idx>>16;
        int ci = kb*64 + s*8 + j;
        wpk[idx] = f2bf(w_dcn[(co*CIc + ci)*9 + k]);
    }
    if (tid < COc) {
        float inv = gamma[tid] * rsqrtf(rvar[tid] + 1e-5f);
        ws[SCALE_OFF+tid] = inv;
        ws[SHIFT_OFF+tid] = beta[tid] - rmean[tid]*inv + b_dcn[tid]*inv;
    }
}

// NCHW fp32 -> permuted NHWC bf16. Block: 32px x 256ci.
__global__ __launch_bounds__(256) void transpose_kernel(const float* __restrict__ x,
                                                        float* __restrict__ ws) {
    __shared__ float tile[256][33];
    int bid = blockIdx.x;                 // Bn*512 = 1024
    int b   = bid >> 9;
    int pxt = bid & 511;                  // 32-pixel group
    const float* xb = x + (size_t)b*CIc*HW + pxt*32;
    int px = threadIdx.x & 31, cg = threadIdx.x >> 5;      // cg in [0,8)
    #pragma unroll 8
    for (int it = 0; it < 32; it++) {
        int ci = it*8 + cg;
        tile[ci][px] = xb[(size_t)ci*HW + px];
    }
    __syncthreads();
    int px2 = threadIdx.x >> 3, oct = threadIdx.x & 7;     // px2 in [0,32)
    u16* xto = (u16*)(ws + XT_OFF) + (((size_t)b*HW + pxt*32 + px2) << 8);
    #pragma unroll
    for (int uu = 0; uu < 4; uu++) {
        int u = uu*8 + oct;
        int cib = (u & 3)*64 + (u >> 2)*8;
        u32x4v v;
        #pragma unroll
        for (int t = 0; t < 4; t++)
            v[t] = pkbf(tile[cib + 2*t][px2], tile[cib + 2*t + 1][px2]);
        *(u32x4v*)(xto + u*8) = v;
    }
}

__device__ __forceinline__ void calc_corners(const float* spy, const float* spxs, const float* smk,
        int k, int p_s, int sub, const u16* xt,
        float& w00, float& w01, float& w10, float& w11,
        const u16*& x00, const u16*& x01, const u16*& x10, const u16*& x11) {
    float pyv = spy[k*64 + p_s], pxv = spxs[k*64 + p_s], mv = smk[k*64 + p_s];
    float y0f = floorf(pyv), x0f = floorf(pxv);
    float ly = pyv - y0f, lx = pxv - x0f;
    int y0 = (int)y0f, x0i = (int)x0f;
    int y1 = y0 + 1, x1i = x0i + 1;
    float wy0 = ((unsigned)y0  < Hh) ? (1.f-ly) : 0.f;
    float wy1 = ((unsigned)y1  < Hh) ? ly       : 0.f;
    float wx0 = ((unsigned)x0i < Ww) ? (1.f-lx) : 0.f;
    float wx1 = ((unsigned)x1i < Ww) ? lx       : 0.f;
    w00 = wy0*wx0*mv; w01 = wy0*wx1*mv; w10 = wy1*wx0*mv; w11 = wy1*wx1*mv;
    int cy0 = min(max(y0,0),Hh-1), cy1 = min(max(y1,0),Hh-1);
    int cx0 = min(max(x0i,0),Ww-1), cx1 = min(max(x1i,0),Ww-1);
    x00 = xt + ((((cy0<<7)+cx0)<<8) + sub*8);
    x01 = xt + ((((cy0<<7)+cx1)<<8) + sub*8);
    x10 = xt + ((((cy1<<7)+cx0)<<8) + sub*8);
    x11 = xt + ((((cy1<<7)+cx1)<<8) + sub*8);
}

// gather 2 units (ubase, ubase+1): 8 dwordx4 loads
#define LOADG(gg, ubase) \
    _Pragma("unroll") for (int t = 0; t < 2; t++) { \
        int o = ((ubase) + t) << 5; \
        gg[t][0] = *(const u32x4v*)(x00 + o); \
        gg[t][1] = *(const u32x4v*)(x01 + o); \
        gg[t][2] = *(const u32x4v*)(x10 + o); \
        gg[t][3] = *(const u32x4v*)(x11 + o); \
    }

// interp + LDS write of 2 units
#define CONSG(gg, ubase, dst) \
    _Pragma("unroll") for (int t = 0; t < 2; t++) { \
        u32x4v vv; \
        _Pragma("unroll") for (int w2 = 0; w2 < 4; w2++) { \
            f32x2 r = unpk(gg[t][0][w2])*w00 + unpk(gg[t][1][w2])*w01 \
                    + unpk(gg[t][2][w2])*w10 + unpk(gg[t][3][w2])*w11; \
            vv[w2] = pkbf(r.x, r.y); \
        } \
        u32 uoff = (((u32)((ubase) + t) << 6) | wsub) ^ wswz; \
        *(u32x4v*)((dst) + wrbase0 + uoff) = vv; \
    }

// one MFMA s-step: 16 MFMA on apre[s&1] x bpre[s&1] (all operands pre-loaded)
#define GEMMSTEP(s) { \
    _Pragma("unroll") for (int bq = 0; bq < 4; bq++) { \
        _Pragma("unroll") for (int mi = 0; mi < 4; mi++) \
            acc[mi][bq] = __builtin_amdgcn_mfma_f32_16x16x32_bf16(apre[(s)&1][mi], bpre[(s)&1][bq], acc[mi][bq], 0,0,0); \
    } }

// depth-2 A prefetch: load A(s+2) into the slot just consumed (s&1) — R14's
// proven parity map; 8 steps/k is even so the k-boundary preserves parity.
#define APREF(s, ptr) { \
    _Pragma("unroll") for (int mi = 0; mi < 4; mi++) \
        apre[(s)&1][mi] = *(const bf16x8*)((ptr) + mi*512); }

// depth-2 B prefetch: load B(sn) fragments from current read buffer
#define BPREF(sn) { \
    u32 inn = ((u32)((sn)*64 + kb*16)) ^ rswz; \
    _Pragma("unroll") for (int bq = 0; bq < 4; bq++) \
        bpre[(sn)&1][bq] = *(const bf16x8*)(base_r + (pxl + bq*16)*512 + inn); }

// Fused: 256 threads / 4 waves (wave = 64co x 64px), dbuf, 1 barrier/k.
// R14 base (A depth-2 parity) + B-fragment prefetch depth 2.
// Step: [fence][MFMA (all-reg operands)][A-pref s+2][B-pref s+1][gather slots].
__global__ __launch_bounds__(256, 2) void fused_kernel(const float* __restrict__ b_off,
                                                       const float* __restrict__ ws,
                                                       float* __restrict__ out) {
    __shared__ __align__(16) char smem[65536 + 3*576*4];
    float* fin  = (float*)smem;               // [32][64] f32, phase A only (aliases buf0)
    float* spy  = (float*)(smem + 65536);
    float* spxs = spy + 576;
    float* smk  = spxs + 576;

    int tid = threadIdx.x;
    int bid = blockIdx.x;
    int tile = (bid & 7)*64 + (bid >> 3);     // XCD-chunked swizzle, 512 blocks
    int b = tile >> 8;
    int pixbase = (tile & 255) * 64;
    int h  = pixbase >> 7;
    int w0 = pixbase & 127;

    const u16* wofp = (const u16*)(ws + WOFP_OFF);
    const u16* wpk  = (const u16*)(ws + WPACK_OFF);
    const u16* xt   = (const u16*)(ws + XT_OFF) + (size_t)b*HW*256;

    int l  = tid & 63;
    int wv = tid >> 6;                        // 0..3
    int kb = l >> 4;
    int pxl = l & 15;
    int aoff = pxl*32 + kb*8;

    // ---------------- phase A: offset conv (depth-1 reg pipeline) ----------------
    {
        int pxa = wv*16 + pxl;
        f32x4 oa0 = {0.f,0.f,0.f,0.f}, oa1 = {0.f,0.f,0.f,0.f};
        #pragma unroll
        for (int k = 0; k < 9; k++) {
            int ky = k/3, kx = k - 3*ky;
            int y  = h + ky - 1;
            int xw = w0 + pxa + kx - 1;
            bool ok = ((unsigned)y < Hh) && ((unsigned)xw < Ww);
            const u16* brow = xt + (((y << 7) + xw) << 8);
            const u16* wk = wofp + k*8192;
            bf16x8 bfC = {};
            if (ok) bfC = *(const bf16x8*)(brow + kb*8);
            bf16x8 a0C = *(const bf16x8*)(wk + aoff);
            bf16x8 a1C = *(const bf16x8*)(wk + 512 + aoff);
            #pragma unroll
            for (int s = 0; s < 8; s++) {
                bf16x8 bfN = {}, a0N = {}, a1N = {};
                if (s < 7) {
                    if (ok) bfN = *(const bf16x8*)(brow + (s+1)*32 + kb*8);
                    a0N = *(const bf16x8*)(wk + (s+1)*1024 + aoff);
                    a1N = *(const bf16x8*)(wk + (s+1)*1024 + 512 + aoff);
                }
                oa0 = __builtin_amdgcn_mfma_f32_16x16x32_bf16(a0C, bfC, oa0, 0,0,0);
                oa1 = __builtin_amdgcn_mfma_f32_16x16x32_bf16(a1C, bfC, oa1, 0,0,0);
                if (s < 7) { bfC = bfN; a0C = a0N; a1C = a1N; }
            }
        }
        #pragma unroll
        for (int r = 0; r < 4; r++) {
            fin[(kb*4 + r)*64 + pxa]      = oa0[r];
            fin[(16 + kb*4 + r)*64 + pxa] = oa1[r];
        }
    }
    __syncthreads();
    for (int idx = tid; idx < 576; idx += 256) {
        int k = idx >> 6, p = idx & 63;
        float dy = fin[(2*k)*64 + p]   + b_off[2*k];
        float dx = fin[(2*k+1)*64 + p] + b_off[2*k+1];
        float mv = fin[(18+k)*64 + p]  + b_off[18+k];
        spy[idx]  = (float)(h - 1 + k/3) + dy;
        spxs[idx] = (float)(w0 + p - 1 + k%3) + dx;
        smk[idx]  = 1.f/(1.f + __expf(-mv));
    }
    __syncthreads();

    // ---------------- phase B ----------------
    int p_s = tid >> 2;                       // staging pixel 0..63
    int sub = tid & 3;                        // 16B sub-slot within 64B unit
    u32 wrbase0 = (u32)p_s*512;
    u32 wsub = (u32)sub << 4;
    u32 wswz = (u32)(p_s & 7) << 4;
    u32 rswz = (u32)(pxl & 7) << 4;

    f32x4 acc[4][4];
    #pragma unroll
    for (int mi = 0; mi < 4; mi++)
        #pragma unroll
        for (int bq = 0; bq < 4; bq++)
            acc[mi][bq] = (f32x4){0.f,0.f,0.f,0.f};

    bf16x8 apre[2][4];
    bf16x8 bpre[2][4];

    // --- prologue: stage k=0 into buf0, preload A(0, s=0,1) ---
    {
        float w00,w01,w10,w11; const u16 *x00,*x01,*x10,*x11;
        calc_corners(spy, spxs, smk, 0, p_s, sub, xt, w00,w01,w10,w11, x00,x01,x10,x11);
        u32x4v ga[2][4], gb[2][4];
        LOADG(ga, 0); LOADG(gb, 2);
        CONSG(ga, 0, smem); CONSG(gb, 2, smem);
        LOADG(ga, 4); LOADG(gb, 6);
        CONSG(ga, 4, smem); CONSG(gb, 6, smem);
    }
    {
        const u16* ap0 = wpk + wv*2048 + aoff;
        #pragma unroll
        for (int mi = 0; mi < 4; mi++) {
            apre[0][mi] = *(const bf16x8*)(ap0 + mi*512);
            apre[1][mi] = *(const bf16x8*)(ap0 + 8192 + mi*512);
        }
    }
    __syncthreads();

    // main loop k = 0..7 (stage k+1), k=8 peeled below
    for (int k = 0; k < 8; k++) {
        const char* base_r = smem + ((k & 1) << 15);
        char* base_w = smem + (((k + 1) & 1) << 15);
        const u16* wkb   = wpk + k*65536 + wv*2048 + aoff;
        const u16* wkb_n = wkb + 65536;

        float w00,w01,w10,w11; const u16 *x00,*x01,*x10,*x11;
        calc_corners(spy, spxs, smk, k+1, p_s, sub, xt, w00,w01,w10,w11, x00,x01,x10,x11);

        BPREF(0);                             // B(0) for this k (buf ready post-barrier)

        u32x4v g0[2][4], g1[2][4];
        #pragma unroll
        for (int s = 0; s < 8; s++) {
            __builtin_amdgcn_sched_barrier(0);
            __builtin_amdgcn_s_setprio(1);
            GEMMSTEP(s);
            __builtin_amdgcn_s_setprio(0);
            // A(s+2) — ahead of gathers in the vmcnt FIFO; slot s&1 just freed
            { const u16* ap = (s < 6) ? (wkb + (s+2)*8192) : (wkb_n + (s-6)*8192); APREF(s, ap); }
            // B(s+1) from LDS (lgkm pipeline, one step of cover)
            if (s < 7) { BPREF(s+1); }
            // gather slots for k+1 (issue/consume; distances 4,4,3,3)
            if (s == 0) { LOADG(g0, 0); }
            if (s == 1) { LOADG(g1, 2); }
            if (s == 4) { CONSG(g0, 0, base_w); LOADG(g0, 4); }
            if (s == 5) { CONSG(g1, 2, base_w); LOADG(g1, 6); }
            if (s == 7) { CONSG(g0, 4, base_w); }
        }
        CONSG(g1, 6, base_w);
        __syncthreads();
    }
    // k = 8 peeled: pure GEMM on buf0
    {
        const char* base_r = smem;
        const u16* wkb = wpk + 8*65536 + wv*2048 + aoff;
        BPREF(0);
        #pragma unroll
        for (int s = 0; s < 8; s++) {
            __builtin_amdgcn_sched_barrier(0);
            __builtin_amdgcn_s_setprio(1);
            GEMMSTEP(s);
            __builtin_amdgcn_s_setprio(0);
            if (s < 6) { const u16* ap = wkb + (s+2)*8192; APREF(s, ap); }
            if (s < 7) { BPREF(s+1); }
        }
    }

    // epilogue: BN + ReLU. D layout: col(px)=pxl, row(co)=kb*4+r
    int rbase = kb*4;
    #pragma unroll
    for (int mi = 0; mi < 4; mi++) {
        #pragma unroll
        for (int r = 0; r < 4; r++) {
            int co = wv*64 + mi*16 + rbase + r;
            float sc = ws[SCALE_OFF+co], sh = ws[SHIFT_OFF+co];
            float* op = out + ((size_t)(b*COc + co))*HW + pixbase + pxl;
            #pragma unroll
            for (int bq = 0; bq < 4; bq++)
                op[bq*16] = fmaxf(acc[mi][bq][r]*sc + sh, 0.f);
        }
    }
}

extern "C" void kernel_launch(void* const* d_in, const int* in_sizes, int n_in,
                              void* d_out, int out_size, void* d_ws, size_t ws_size,
                              hipStream_t stream) {
    const float* x     = (const float*)d_in[0];
    const float* w_off = (const float*)d_in[1];
    const float* b_off = (const float*)d_in[2];
    const float* w_dcn = (const float*)d_in[3];
    const float* b_dcn = (const float*)d_in[4];
    const float* gamma = (const float*)d_in[5];
    const float* beta  = (const float*)d_in[6];
    const float* rmean = (const float*)d_in[7];
    const float* rvar  = (const float*)d_in[8];
    float* out = (float*)d_out;
    float* ws  = (float*)d_ws;

    prep_kernel<<<512, 256, 0, stream>>>(w_off, w_dcn, b_dcn, gamma, beta, rmean, rvar, ws);
    transpose_kernel<<<1024, 256, 0, stream>>>(x, ws);
    fused_kernel<<<512, 256, 0, stream>>>(b_off, ws, out);
}

// Round 19
// 100.076 us; speedup vs baseline: 1.4899x; 1.1043x over previous
//
#include <hip/hip_runtime.h>
#include <math.h>

#define Bn 2
#define CIc 256
#define COc 256
#define Hh 128
#define Ww 128
#define HW (Hh*Ww)

typedef unsigned short u16;
typedef unsigned int u32;
typedef __bf16 bf16x8 __attribute__((ext_vector_type(8)));
typedef float  f32x4  __attribute__((ext_vector_type(4)));
typedef float  f32x2  __attribute__((ext_vector_type(2)));
typedef u32    u32x4v __attribute__((ext_vector_type(4)));

// ws layout (float offsets)
#define WOFP_OFF  0          // 9*8*32*4*8 u16  = 36864 f
#define WPACK_OFF 36864      // 9*8*256*4*8 u16 = 294912 f
#define SCALE_OFF 331776
#define SHIFT_OFF 332032
#define XT_OFF    332288     // u16 xt[B][HW][256]
// xt pixel-row: 32 units of 16B; unit u holds ci chunk (u&3)*64 + (u>>2)*8 .. +8
// A-packs use the same map (unit s*4+kb <-> ci = kb*64 + s*8 + j) so the permutation cancels.

__device__ __forceinline__ u16 f2bf(float f) {
    u32 u = __builtin_bit_cast(u32, f);
    return (u16)((u + 0x7FFFu + ((u >> 16) & 1u)) >> 16);
}
__device__ __forceinline__ u32 pkbf(float lo, float hi) {
    __bf16 a = (__bf16)lo, b = (__bf16)hi;            // fuses to v_cvt_pk_bf16_f32
    return (u32)__builtin_bit_cast(u16, a) | ((u32)__builtin_bit_cast(u16, b) << 16);
}
__device__ __forceinline__ f32x2 unpk(u32 u) {
    f32x2 r;
    r.x = __builtin_bit_cast(float, u << 16);
    r.y = __builtin_bit_cast(float, u & 0xFFFF0000u);
    return r;
}

__global__ void prep_kernel(const float* __restrict__ w_off,
                            const float* __restrict__ w_dcn,
                            const float* __restrict__ b_dcn,
                            const float* __restrict__ gamma,
                            const float* __restrict__ beta,
                            const float* __restrict__ rmean,
                            const float* __restrict__ rvar,
                            float* __restrict__ ws) {
    int tid = blockIdx.x*blockDim.x + threadIdx.x;
    int nth = gridDim.x*blockDim.x;
    u16* wofp = (u16*)(ws + WOFP_OFF);
    u16* wpk  = (u16*)(ws + WPACK_OFF);
    for (int idx = tid; idx < 9*8*32*4*8; idx += nth) {
        int j = idx & 7, kb = (idx>>3)&3, co = (idx>>5)&31, s = (idx>>10)&7, k = idx>>13;
        int ci = kb*64 + s*8 + j;
        float v = (co < 27) ? w_off[(co*CIc + ci)*9 + k] : 0.f;
        wofp[idx] = f2bf(v);
    }
    for (int idx = tid; idx < 9*8*256*4*8; idx += nth) {
        int j = idx & 7, kb = (idx>>3)&3, co = (idx>>5)&255, s = (idx>>13)&7, k = idx>>16;
        int ci = kb*64 + s*8 + j;
        wpk[idx] = f2bf(w_dcn[(co*CIc + ci)*9 + k]);
    }
    if (tid < COc) {
        float inv = gamma[tid] * rsqrtf(rvar[tid] + 1e-5f);
        ws[SCALE_OFF+tid] = inv;
        ws[SHIFT_OFF+tid] = beta[tid] - rmean[tid]*inv + b_dcn[tid]*inv;
    }
}

// NCHW fp32 -> permuted NHWC bf16. Block: 32px x 256ci.
__global__ __launch_bounds__(256) void transpose_kernel(const float* __restrict__ x,
                                                        float* __restrict__ ws) {
    __shared__ float tile[256][33];
    int bid = blockIdx.x;                 // Bn*512 = 1024
    int b   = bid >> 9;
    int pxt = bid & 511;                  // 32-pixel group
    const float* xb = x + (size_t)b*CIc*HW + pxt*32;
    int px = threadIdx.x & 31, cg = threadIdx.x >> 5;      // cg in [0,8)
    #pragma unroll 8
    for (int it = 0; it < 32; it++) {
        int ci = it*8 + cg;
        tile[ci][px] = xb[(size_t)ci*HW + px];
    }
    __syncthreads();
    int px2 = threadIdx.x >> 3, oct = threadIdx.x & 7;     // px2 in [0,32)
    u16* xto = (u16*)(ws + XT_OFF) + (((size_t)b*HW + pxt*32 + px2) << 8);
    #pragma unroll
    for (int uu = 0; uu < 4; uu++) {
        int u = uu*8 + oct;
        int cib = (u & 3)*64 + (u >> 2)*8;
        u32x4v v;
        #pragma unroll
        for (int t = 0; t < 4; t++)
            v[t] = pkbf(tile[cib + 2*t][px2], tile[cib + 2*t + 1][px2]);
        *(u32x4v*)(xto + u*8) = v;
    }
}

__device__ __forceinline__ void calc_corners(const float* spy, const float* spxs, const float* smk,
        int k, int p_s, int sub, const u16* xt,
        float& w00, float& w01, float& w10, float& w11,
        const u16*& x00, const u16*& x01, const u16*& x10, const u16*& x11) {
    float pyv = spy[k*64 + p_s], pxv = spxs[k*64 + p_s], mv = smk[k*64 + p_s];
    float y0f = floorf(pyv), x0f = floorf(pxv);
    float ly = pyv - y0f, lx = pxv - x0f;
    int y0 = (int)y0f, x0i = (int)x0f;
    int y1 = y0 + 1, x1i = x0i + 1;
    float wy0 = ((unsigned)y0  < Hh) ? (1.f-ly) : 0.f;
    float wy1 = ((unsigned)y1  < Hh) ? ly       : 0.f;
    float wx0 = ((unsigned)x0i < Ww) ? (1.f-lx) : 0.f;
    float wx1 = ((unsigned)x1i < Ww) ? lx       : 0.f;
    w00 = wy0*wx0*mv; w01 = wy0*wx1*mv; w10 = wy1*wx0*mv; w11 = wy1*wx1*mv;
    int cy0 = min(max(y0,0),Hh-1), cy1 = min(max(y1,0),Hh-1);
    int cx0 = min(max(x0i,0),Ww-1), cx1 = min(max(x1i,0),Ww-1);
    x00 = xt + ((((cy0<<7)+cx0)<<8) + sub*8);
    x01 = xt + ((((cy0<<7)+cx1)<<8) + sub*8);
    x10 = xt + ((((cy1<<7)+cx0)<<8) + sub*8);
    x11 = xt + ((((cy1<<7)+cx1)<<8) + sub*8);
}

// gather 2 units (ubase, ubase+1): 8 dwordx4 loads
#define LOADG(gg, ubase) \
    _Pragma("unroll") for (int t = 0; t < 2; t++) { \
        int o = ((ubase) + t) << 5; \
        gg[t][0] = *(const u32x4v*)(x00 + o); \
        gg[t][1] = *(const u32x4v*)(x01 + o); \
        gg[t][2] = *(const u32x4v*)(x10 + o); \
        gg[t][3] = *(const u32x4v*)(x11 + o); \
    }

// interp + LDS write of 2 units
#define CONSG(gg, ubase, dst) \
    _Pragma("unroll") for (int t = 0; t < 2; t++) { \
        u32x4v vv; \
        _Pragma("unroll") for (int w2 = 0; w2 < 4; w2++) { \
            f32x2 r = unpk(gg[t][0][w2])*w00 + unpk(gg[t][1][w2])*w01 \
                    + unpk(gg[t][2][w2])*w10 + unpk(gg[t][3][w2])*w11; \
            vv[w2] = pkbf(r.x, r.y); \
        } \
        u32 uoff = (((u32)((ubase) + t) << 6) | wsub) ^ wswz; \
        *(u32x4v*)((dst) + wrbase0 + uoff) = vv; \
    }

// one MFMA s-step: 16 MFMA on apre[s&1] x bpre[s&1] (all operands pre-loaded)
#define GEMMSTEP(s) { \
    _Pragma("unroll") for (int bq = 0; bq < 4; bq++) { \
        _Pragma("unroll") for (int mi = 0; mi < 4; mi++) \
            acc[mi][bq] = __builtin_amdgcn_mfma_f32_16x16x32_bf16(apre[(s)&1][mi], bpre[(s)&1][bq], acc[mi][bq], 0,0,0); \
    } }

// depth-2 A prefetch: load A(s+2) into the slot just consumed (s&1)
#define APREF(s, ptr) { \
    _Pragma("unroll") for (int mi = 0; mi < 4; mi++) \
        apre[(s)&1][mi] = *(const bf16x8*)((ptr) + mi*512); }

// depth-2 B prefetch: load B(sn) fragments from current read buffer
#define BPREF(sn) { \
    u32 inn = ((u32)((sn)*64 + kb*16)) ^ rswz; \
    _Pragma("unroll") for (int bq = 0; bq < 4; bq++) \
        bpre[(sn)&1][bq] = *(const bf16x8*)(base_r + (pxl + bq*16)*512 + inn); }

// Fused: 256 threads / 4 waves (wave = 64co x 64px), dbuf, 1 barrier/k.
// Phase A NOW LDS-STAGED: per ky, stage xt rows (y, w0-1..w0+64) coalesced
// into smem (33KB, XOR-swizzled), then 3 taps read B-frags via ds_read_b128.
// Phase B = R18 verbatim.
__global__ __launch_bounds__(256, 2) void fused_kernel(const float* __restrict__ b_off,
                                                       const float* __restrict__ ws,
                                                       float* __restrict__ out) {
    __shared__ __align__(16) char smem[65536 + 3*576*4];
    float* finA = (float*)(smem + 36864);     // [32][64] f32 at 36864..45056 (in buf1, dead then)
    float* spy  = (float*)(smem + 65536);
    float* spxs = spy + 576;
    float* smk  = spxs + 576;

    int tid = threadIdx.x;
    int bid = blockIdx.x;
    int tile = (bid & 7)*64 + (bid >> 3);     // XCD-chunked swizzle, 512 blocks
    int b = tile >> 8;
    int pixbase = (tile & 255) * 64;
    int h  = pixbase >> 7;
    int w0 = pixbase & 127;

    const u16* wofp = (const u16*)(ws + WOFP_OFF);
    const u16* wpk  = (const u16*)(ws + WPACK_OFF);
    const u16* xt   = (const u16*)(ws + XT_OFF) + (size_t)b*HW*256;

    int l  = tid & 63;
    int wv = tid >> 6;                        // 0..3
    int kb = l >> 4;
    int pxl = l & 15;
    int aoff = pxl*32 + kb*8;

    // ---------------- phase A: offset conv, LDS-staged window ----------------
    {
        int pxa = wv*16 + pxl;
        f32x4 oa0 = {0.f,0.f,0.f,0.f}, oa1 = {0.f,0.f,0.f,0.f};
        for (int ky = 0; ky < 3; ky++) {
            int y = h + ky - 1;
            if ((unsigned)y < Hh) {           // block-uniform branch
                __syncthreads();              // prior taps' LDS reads done
                // stage rows (y, w0-1 .. w0+64): 66 rows x 512B, coalesced, zero-pad edges
                const u16* xrow = xt + (((size_t)y << 7) << 8);
                for (int c = tid; c < 66*32; c += 256) {
                    int rr = c >> 5, slot = c & 31;
                    int xw = w0 - 1 + rr;
                    u32x4v v = {};
                    if ((unsigned)xw < Ww) v = *(const u32x4v*)(xrow + ((size_t)xw << 8) + slot*8);
                    u32 off = ((u32)(rr*512 + slot*16)) ^ (((u32)(rr & 7)) << 4);
                    *(u32x4v*)(smem + off) = v;
                }
                __syncthreads();
                #pragma unroll
                for (int kx = 0; kx < 3; kx++) {
                    int k = ky*3 + kx;
                    const u16* wk = wofp + k*8192;
                    int rr = pxa + kx;        // staged row index (w0-1 origin)
                    u32 rbase = (u32)rr * 512;
                    u32 rsw = ((u32)(rr & 7)) << 4;
                    #pragma unroll
                    for (int s = 0; s < 8; s++) {
                        u32 off = (rbase + (u32)((s*4 + kb)*16)) ^ rsw;
                        bf16x8 bf = *(const bf16x8*)(smem + off);
                        bf16x8 a0 = *(const bf16x8*)(wk + s*1024 + aoff);
                        bf16x8 a1 = *(const bf16x8*)(wk + s*1024 + 512 + aoff);
                        oa0 = __builtin_amdgcn_mfma_f32_16x16x32_bf16(a0, bf, oa0, 0,0,0);
                        oa1 = __builtin_amdgcn_mfma_f32_16x16x32_bf16(a1, bf, oa1, 0,0,0);
                    }
                }
            }
        }
        __syncthreads();                      // staged-window reads done; finA writes begin
        #pragma unroll
        for (int r = 0; r < 4; r++) {
            finA[(kb*4 + r)*64 + pxa]      = oa0[r];
            finA[(16 + kb*4 + r)*64 + pxa] = oa1[r];
        }
    }
    __syncthreads();
    for (int idx = tid; idx < 576; idx += 256) {
        int k = idx >> 6, p = idx & 63;
        float dy = finA[(2*k)*64 + p]   + b_off[2*k];
        float dx = finA[(2*k+1)*64 + p] + b_off[2*k+1];
        float mv = finA[(18+k)*64 + p]  + b_off[18+k];
        spy[idx]  = (float)(h - 1 + k/3) + dy;
        spxs[idx] = (float)(w0 + p - 1 + k%3) + dx;
        smk[idx]  = 1.f/(1.f + __expf(-mv));
    }
    __syncthreads();

    // ---------------- phase B (R18 verbatim) ----------------
    int p_s = tid >> 2;                       // staging pixel 0..63
    int sub = tid & 3;                        // 16B sub-slot within 64B unit
    u32 wrbase0 = (u32)p_s*512;
    u32 wsub = (u32)sub << 4;
    u32 wswz = (u32)(p_s & 7) << 4;
    u32 rswz = (u32)(pxl & 7) << 4;

    f32x4 acc[4][4];
    #pragma unroll
    for (int mi = 0; mi < 4; mi++)
        #pragma unroll
        for (int bq = 0; bq < 4; bq++)
            acc[mi][bq] = (f32x4){0.f,0.f,0.f,0.f};

    bf16x8 apre[2][4];
    bf16x8 bpre[2][4];

    // --- prologue: stage k=0 into buf0, preload A(0, s=0,1) ---
    {
        float w00,w01,w10,w11; const u16 *x00,*x01,*x10,*x11;
        calc_corners(spy, spxs, smk, 0, p_s, sub, xt, w00,w01,w10,w11, x00,x01,x10,x11);
        u32x4v ga[2][4], gb[2][4];
        LOADG(ga, 0); LOADG(gb, 2);
        CONSG(ga, 0, smem); CONSG(gb, 2, smem);
        LOADG(ga, 4); LOADG(gb, 6);
        CONSG(ga, 4, smem); CONSG(gb, 6, smem);
    }
    {
        const u16* ap0 = wpk + wv*2048 + aoff;
        #pragma unroll
        for (int mi = 0; mi < 4; mi++) {
            apre[0][mi] = *(const bf16x8*)(ap0 + mi*512);
            apre[1][mi] = *(const bf16x8*)(ap0 + 8192 + mi*512);
        }
    }
    __syncthreads();

    // main loop k = 0..7 (stage k+1), k=8 peeled below
    for (int k = 0; k < 8; k++) {
        const char* base_r = smem + ((k & 1) << 15);
        char* base_w = smem + (((k + 1) & 1) << 15);
        const u16* wkb   = wpk + k*65536 + wv*2048 + aoff;
        const u16* wkb_n = wkb + 65536;

        float w00,w01,w10,w11; const u16 *x00,*x01,*x10,*x11;
        calc_corners(spy, spxs, smk, k+1, p_s, sub, xt, w00,w01,w10,w11, x00,x01,x10,x11);

        BPREF(0);                             // B(0) for this k (buf ready post-barrier)

        u32x4v g0[2][4], g1[2][4];
        #pragma unroll
        for (int s = 0; s < 8; s++) {
            __builtin_amdgcn_sched_barrier(0);
            __builtin_amdgcn_s_setprio(1);
            GEMMSTEP(s);
            __builtin_amdgcn_s_setprio(0);
            // A(s+2) — ahead of gathers in the vmcnt FIFO; slot s&1 just freed
            { const u16* ap = (s < 6) ? (wkb + (s+2)*8192) : (wkb_n + (s-6)*8192); APREF(s, ap); }
            // B(s+1) from LDS (lgkm pipeline, one step of cover)
            if (s < 7) { BPREF(s+1); }
            // gather slots for k+1 (issue/consume; distances 4,4,3,3)
            if (s == 0) { LOADG(g0, 0); }
            if (s == 1) { LOADG(g1, 2); }
            if (s == 4) { CONSG(g0, 0, base_w); LOADG(g0, 4); }
            if (s == 5) { CONSG(g1, 2, base_w); LOADG(g1, 6); }
            if (s == 7) { CONSG(g0, 4, base_w); }
        }
        CONSG(g1, 6, base_w);
        __syncthreads();
    }
    // k = 8 peeled: pure GEMM on buf0
    {
        const char* base_r = smem;
        const u16* wkb = wpk + 8*65536 + wv*2048 + aoff;
        BPREF(0);
        #pragma unroll
        for (int s = 0; s < 8; s++) {
            __builtin_amdgcn_sched_barrier(0);
            __builtin_amdgcn_s_setprio(1);
            GEMMSTEP(s);
            __builtin_amdgcn_s_setprio(0);
            if (s < 6) { const u16* ap = wkb + (s+2)*8192; APREF(s, ap); }
            if (s < 7) { BPREF(s+1); }
        }
    }

    // epilogue: BN + ReLU. D layout: col(px)=pxl, row(co)=kb*4+r
    int rbase = kb*4;
    #pragma unroll
    for (int mi = 0; mi < 4; mi++) {
        #pragma unroll
        for (int r = 0; r < 4; r++) {
            int co = wv*64 + mi*16 + rbase + r;
            float sc = ws[SCALE_OFF+co], sh = ws[SHIFT_OFF+co];
            float* op = out + ((size_t)(b*COc + co))*HW + pixbase + pxl;
            #pragma unroll
            for (int bq = 0; bq < 4; bq++)
                op[bq*16] = fmaxf(acc[mi][bq][r]*sc + sh, 0.f);
        }
    }
}

extern "C" void kernel_launch(void* const* d_in, const int* in_sizes, int n_in,
                              void* d_out, int out_size, void* d_ws, size_t ws_size,
                              hipStream_t stream) {
    const float* x     = (const float*)d_in[0];
    const float* w_off = (const float*)d_in[1];
    const float* b_off = (const float*)d_in[2];
    const float* w_dcn = (const float*)d_in[3];
    const float* b_dcn = (const float*)d_in[4];
    const float* gamma = (const float*)d_in[5];
    const float* beta  = (const float*)d_in[6];
    const float* rmean = (const float*)d_in[7];
    const float* rvar  = (const float*)d_in[8];
    float* out = (float*)d_out;
    float* ws  = (float*)d_ws;

    prep_kernel<<<512, 256, 0, stream>>>(w_off, w_dcn, b_dcn, gamma, beta, rmean, rvar, ws);
    transpose_kernel<<<1024, 256, 0, stream>>>(x, ws);
    fused_kernel<<<512, 256, 0, stream>>>(b_off, ws, out);
}